// Round 18
// baseline (80.469 us; speedup 1.0000x reference)
//
#include <hip/hip_runtime.h>
#include <math.h>

#define BB 16
#define TT 24
#define NN 128
#define DD 64
#define PTOT (BB * TT * NN)   // 49152 positions
#define P64  (PTOT * 64)      // elements per (B,T,N,64) buffer

typedef __attribute__((ext_vector_type(8))) short bf16x8;
typedef __attribute__((ext_vector_type(4))) float f32x4;
typedef __attribute__((ext_vector_type(16))) float f32x16;

__device__ __forceinline__ unsigned cvt_pk_bf16(float a, float b) {
    unsigned r;
    asm("v_cvt_pk_bf16_f32 %0, %1, %2" : "=v"(r) : "v"(a), "v"(b));
    return r;   // low16 = bf16(a), high16 = bf16(b)
}
__device__ __forceinline__ void unpack8(uint4 u, float* f) {
    f[0] = __builtin_bit_cast(float, u.x << 16);
    f[1] = __builtin_bit_cast(float, u.x & 0xFFFF0000u);
    f[2] = __builtin_bit_cast(float, u.y << 16);
    f[3] = __builtin_bit_cast(float, u.y & 0xFFFF0000u);
    f[4] = __builtin_bit_cast(float, u.z << 16);
    f[5] = __builtin_bit_cast(float, u.z & 0xFFFF0000u);
    f[6] = __builtin_bit_cast(float, u.w << 16);
    f[7] = __builtin_bit_cast(float, u.w & 0xFFFF0000u);
}
__device__ __forceinline__ uint4 pack8(const float* f) {
    uint4 o;
    o.x = cvt_pk_bf16(f[0], f[1]);
    o.y = cvt_pk_bf16(f[2], f[3]);
    o.z = cvt_pk_bf16(f[4], f[5]);
    o.w = cvt_pk_bf16(f[6], f[7]);
    return o;
}
__device__ __forceinline__ float fast_exp2(float x) {
#if __has_builtin(__builtin_amdgcn_exp2f)
    return __builtin_amdgcn_exp2f(x);
#else
    return exp2f(x);
#endif
}
__device__ __forceinline__ f32x16 zero16() {
    f32x16 z;
    #pragma unroll
    for (int i = 0; i < 16; ++i) z[i] = 0.f;
    return z;
}
// build one bf16x8 weight fragment from fp32 W[k][n] (k rows of 64):
// element jj = W[(kb+jj)*64 + n], packed RNE via cvt_pk.
__device__ __forceinline__ bf16x8 wfrag64(const float* __restrict__ W,
                                          int kb, int n) {
    const float v0 = W[(kb + 0) * 64 + n];
    const float v1 = W[(kb + 1) * 64 + n];
    const float v2 = W[(kb + 2) * 64 + n];
    const float v3 = W[(kb + 3) * 64 + n];
    const float v4 = W[(kb + 4) * 64 + n];
    const float v5 = W[(kb + 5) * 64 + n];
    const float v6 = W[(kb + 6) * 64 + n];
    const float v7 = W[(kb + 7) * 64 + n];
    uint4 u;
    u.x = cvt_pk_bf16(v0, v1);
    u.y = cvt_pk_bf16(v2, v3);
    u.z = cvt_pk_bf16(v4, v5);
    u.w = cvt_pk_bf16(v6, v7);
    return __builtin_bit_cast(bf16x8, u);
}

// ---------------------------------------------------------------------------
// Kernel 1: FUSED 6-way QKV projection + MFMA spatial attention.
// r14-best structure (spill-free 8-deep named-register staging, transposed
// V in LDS) + NEW: weight prep INLINED -- each thread builds its 18 weight
// fragments directly from the original fp32 weights (144 strided loads,
// L2-resident, issued in the prologue; hidden under staging latency).
// The separate wprep kernel is deleted (-1 launch, -1 gap).
// One block per (b,t): 128 positions, 512 threads (8 waves).
// Barriers: relaxed lgkmcnt-only per mt. LDS: 61,952 B. bounds(512,2).
// ---------------------------------------------------------------------------
__global__ __launch_bounds__(512, 2) void fused_sattn(
    const float* __restrict__ X, const float* __restrict__ TLE,
    const float* __restrict__ W0, const float* __restrict__ W1,
    const float* __restrict__ W2, const float* __restrict__ W3,
    const float* __restrict__ W4, const float* __restrict__ W5,
    const float* __restrict__ b0, const float* __restrict__ b1,
    const float* __restrict__ b2, const float* __restrict__ b3,
    const float* __restrict__ b4, const float* __restrict__ b5,
    unsigned short* __restrict__ qt, unsigned short* __restrict__ kt,
    unsigned short* __restrict__ vt,
    unsigned short* __restrict__ HS)
{
    __shared__ __align__(16) unsigned short xe[2][16][200];   // staged XE tile
    __shared__ __align__(16) unsigned short qq[128 * 64];     // swizzled bf16
    __shared__ __align__(16) unsigned short kk[128 * 64];
    __shared__ __align__(16) unsigned short vvT[64 * 128];    // V transposed
    const int tid = threadIdx.x;
    const long p0 = (long)blockIdx.x * 128;
    const int w = tid >> 6, l = tid & 63, quad = l >> 4, l16 = l & 15;
    const int nt = w >> 1;               // channel tile 0..3
    const int mg = (w & 1) * 3;          // 0 = spatial q/k/v, 3 = temporal

    // ---- per-thread staging geometry (same for every tile) ----
    int mj[3], kj[3];
    const float* srcb[3];   // tile-0 source address; tile t adds row stride
    long rstride[3];        // floats to advance per tile (16 rows)
    #pragma unroll
    for (int j = 0; j < 3; ++j) {
        const int f = (j * 512 + tid) * 2;
        mj[j] = f / 192;
        kj[j] = f % 192;
        if (kj[j] < 64) { srcb[j] = X + (p0 + mj[j]) * 64 + kj[j];  rstride[j] = 16 * 64; }
        else            { srcb[j] = TLE + (p0 + mj[j]) * 128 + (kj[j] - 64); rstride[j] = 16 * 128; }
    }

    // ---- 8-deep staging in NAMED registers (no array -> no scratch) ----
    uint2 t0a, t0b, t0c, t1a, t1b, t1c, t2a, t2b, t2c, t3a, t3b, t3c,
          t4a, t4b, t4c, t5a, t5b, t5c, t6a, t6b, t6c, t7a, t7b, t7c;
#define LOADT(T, A, B, C) \
    A = *reinterpret_cast<const uint2*>(srcb[0] + (long)(T) * rstride[0]); \
    B = *reinterpret_cast<const uint2*>(srcb[1] + (long)(T) * rstride[1]); \
    C = *reinterpret_cast<const uint2*>(srcb[2] + (long)(T) * rstride[2]);
    LOADT(0, t0a, t0b, t0c)
    LOADT(1, t1a, t1b, t1c)
    LOADT(2, t2a, t2b, t2c)
    LOADT(3, t3a, t3b, t3c)
    LOADT(4, t4a, t4b, t4c)
    LOADT(5, t5a, t5b, t5c)
    LOADT(6, t6a, t6b, t6c)
    LOADT(7, t7a, t7b, t7c)
#undef LOADT

    // staging write from registers (by value -> always register operands)
    auto swr = [&](uint2 a, uint2 b, uint2 c, int buf) {
        *reinterpret_cast<unsigned*>(&xe[buf][mj[0]][kj[0]]) =
            cvt_pk_bf16(__builtin_bit_cast(float, a.x), __builtin_bit_cast(float, a.y));
        *reinterpret_cast<unsigned*>(&xe[buf][mj[1]][kj[1]]) =
            cvt_pk_bf16(__builtin_bit_cast(float, b.x), __builtin_bit_cast(float, b.y));
        *reinterpret_cast<unsigned*>(&xe[buf][mj[2]][kj[2]]) =
            cvt_pk_bf16(__builtin_bit_cast(float, c.x), __builtin_bit_cast(float, c.y));
    };

    // ---- build this wave's 18 weight fragments INLINE from fp32 weights ----
    const float* Wsel[6] = {W0, W1, W2, W3, W4, W5};
    bf16x8 wf[3][6];
    {
        const int n = nt * 16 + l16;
        #pragma unroll
        for (int mi = 0; mi < 3; ++mi) {
            const float* Wm = Wsel[mg + mi];
            #pragma unroll
            for (int kc = 0; kc < 6; ++kc)
                wf[mi][kc] = wfrag64(Wm, kc * 32 + quad * 8, n);
        }
    }

    const float* bias_p[6] = {b0, b1, b2, b3, b4, b5};
    float4 bias[3];
    #pragma unroll
    for (int mi = 0; mi < 3; ++mi)
        bias[mi] = *reinterpret_cast<const float4*>(&bias_p[mg + mi][nt * 16 + quad * 4]);

    swr(t0a, t0b, t0c, 0);
    __syncthreads();

    const int chBase = nt * 16 + quad * 4;          // channel base
    const int chunkW = nt * 2 + (quad >> 1);        // 8-ch chunk (q/k LDS)
    const int chSub  = (quad & 1) * 4;              // offset within chunk
    const float cs = 0.35355339059327373f * 1.4426950408889634f;  // scale*log2e

    #pragma unroll
    for (int mt = 0; mt < 8; ++mt) {
        switch (mt) {                                // stage tile mt+1 (literal)
            case 0: swr(t1a, t1b, t1c, 1); break;
            case 1: swr(t2a, t2b, t2c, 0); break;
            case 2: swr(t3a, t3b, t3c, 1); break;
            case 3: swr(t4a, t4b, t4c, 0); break;
            case 4: swr(t5a, t5b, t5c, 1); break;
            case 5: swr(t6a, t6b, t6c, 0); break;
            case 6: swr(t7a, t7b, t7c, 1); break;
            default: break;
        }

        bf16x8 A[6];
        #pragma unroll
        for (int kc = 0; kc < 6; ++kc)
            A[kc] = *reinterpret_cast<const bf16x8*>(
                &xe[mt & 1][l16][kc * 32 + quad * 8]);

        // bias folded into accumulator init (C operand of MFMA)
        f32x4 acc[3];
        #pragma unroll
        for (int mi = 0; mi < 3; ++mi)
            acc[mi] = (f32x4){bias[mi].x, bias[mi].y, bias[mi].z, bias[mi].w};
        #pragma unroll
        for (int kc = 0; kc < 6; ++kc)
            #pragma unroll
            for (int mi = 0; mi < 3; ++mi)
                acc[mi] = __builtin_amdgcn_mfma_f32_16x16x32_bf16(
                    wf[mi][kc], A[kc], acc[mi], 0, 0, 0);

        const int pos = mt * 16 + l16;              // lane's position (C/D col)
        if (mg == 0) {                              // spatial -> LDS
            const int sw = pos * 64 + ((chunkW ^ (pos & 7)) << 3) + chSub;
            uint2 uq;
            uq.x = cvt_pk_bf16(fmaxf(acc[0][0], 0.f) * cs, fmaxf(acc[0][1], 0.f) * cs);
            uq.y = cvt_pk_bf16(fmaxf(acc[0][2], 0.f) * cs, fmaxf(acc[0][3], 0.f) * cs);
            *reinterpret_cast<uint2*>(&qq[sw]) = uq;
            uint2 uk;
            uk.x = cvt_pk_bf16(fmaxf(acc[1][0], 0.f), fmaxf(acc[1][1], 0.f));
            uk.y = cvt_pk_bf16(fmaxf(acc[1][2], 0.f), fmaxf(acc[1][3], 0.f));
            *reinterpret_cast<uint2*>(&kk[sw]) = uk;
            // V -> TRANSPOSED LDS: vvT[ch*128 + (pos ^ ((ch&7)<<3))]
            const unsigned pv0 = cvt_pk_bf16(fmaxf(acc[2][0], 0.f), fmaxf(acc[2][1], 0.f));
            const unsigned pv1 = cvt_pk_bf16(fmaxf(acc[2][2], 0.f), fmaxf(acc[2][3], 0.f));
            vvT[(chBase + 0) * 128 + (pos ^ (((chBase + 0) & 7) << 3))] = (unsigned short)pv0;
            vvT[(chBase + 1) * 128 + (pos ^ (((chBase + 1) & 7) << 3))] = (unsigned short)(pv0 >> 16);
            vvT[(chBase + 2) * 128 + (pos ^ (((chBase + 2) & 7) << 3))] = (unsigned short)pv1;
            vvT[(chBase + 3) * 128 + (pos ^ (((chBase + 3) & 7) << 3))] = (unsigned short)(pv1 >> 16);
        } else {                                    // temporal -> global bf16
            unsigned short* dstT[3] = {qt, kt, vt};
            const long gp = (p0 + pos) * 64 + chBase;
            #pragma unroll
            for (int mi = 0; mi < 3; ++mi) {
                uint2 u;
                u.x = cvt_pk_bf16(fmaxf(acc[mi][0], 0.f), fmaxf(acc[mi][1], 0.f));
                u.y = cvt_pk_bf16(fmaxf(acc[mi][2], 0.f), fmaxf(acc[mi][3], 0.f));
                *reinterpret_cast<uint2*>(&dstT[mi][gp]) = u;
            }
        }
        // LDS-only barrier (no vmcnt drain of the temporal stores).
        __builtin_amdgcn_sched_barrier(0);
        asm volatile("s_waitcnt lgkmcnt(0)" ::: "memory");
        __builtin_amdgcn_s_barrier();
        __builtin_amdgcn_sched_barrier(0);
    }
    // (the mt==7 pass of the barrier above is the inter-phase barrier)

    // ---------------- MFMA attention phase: wave w == head w ----------------
    const int h  = w;
    const int hi = l >> 5;            // lane half (0/1)
    const int ln = l & 31;            // lane-in-half
    bf16x8 zf = {};
    const int swz = (h ^ (ln & 7)) << 3;

    // P^T-tile -> PV B-frag repack + 2 PV MFMAs.
    auto pvstep = [&](f32x16& st, const bf16x8& va0, const bf16x8& va1,
                      f32x16& oacc) {
        const unsigned P0 = cvt_pk_bf16(st[0],  st[1]);
        const unsigned P1 = cvt_pk_bf16(st[2],  st[3]);
        const unsigned P2 = cvt_pk_bf16(st[4],  st[5]);
        const unsigned P3 = cvt_pk_bf16(st[6],  st[7]);
        const unsigned P4 = cvt_pk_bf16(st[8],  st[9]);
        const unsigned P5 = cvt_pk_bf16(st[10], st[11]);
        const unsigned P6 = cvt_pk_bf16(st[12], st[13]);
        const unsigned P7 = cvt_pk_bf16(st[14], st[15]);
        const unsigned V0 = __shfl_xor(hi ? P0 : P2, 32);
        const unsigned V1 = __shfl_xor(hi ? P1 : P3, 32);
        const unsigned V2 = __shfl_xor(hi ? P4 : P6, 32);
        const unsigned V3 = __shfl_xor(hi ? P5 : P7, 32);
        uint4 fe, fo;
        fe.x = hi ? V0 : P0; fe.y = hi ? V1 : P1;
        fe.z = hi ? P2 : V0; fe.w = hi ? P3 : V1;
        fo.x = hi ? V2 : P4; fo.y = hi ? V3 : P5;
        fo.z = hi ? P6 : V2; fo.w = hi ? P7 : V3;
        oacc = __builtin_amdgcn_mfma_f32_32x32x16_bf16(
            va0, __builtin_bit_cast(bf16x8, fe), oacc, 0, 0, 0);
        oacc = __builtin_amdgcn_mfma_f32_32x32x16_bf16(
            va1, __builtin_bit_cast(bf16x8, fo), oacc, 0, 0, 0);
    };

    // K A-frags (4 m-tiles): lane ln holds K[row=t*32+ln][d=hi*8+j];
    // hi=1 half is the d=8..15 zero padding.
    bf16x8 kf[4];
    #pragma unroll
    for (int t = 0; t < 4; ++t)
        kf[t] = hi ? zf : *reinterpret_cast<const bf16x8*>(&kk[(t * 32 + ln) * 64 + swz]);

    // V^T A-frags (8 m-chunks): lane ln<8 = dim d; one ds_read_b128 each
    // (8 contiguous swizzled positions), rows d>=8 zero.
    bf16x8 vf[8];
    #pragma unroll
    for (int c = 0; c < 8; ++c) {
        bf16x8 f = zf;
        if (ln < 8) {
            const int base = (h * 8 + ln) * 128 + ((c * 16 + hi * 8) ^ (ln << 3));
            f = *reinterpret_cast<const bf16x8*>(&vvT[base]);
        }
        vf[c] = f;
    }

    #pragma unroll
    for (int ntq = 0; ntq < 4; ++ntq) {
        const int qrow = ntq * 32 + ln;
        bf16x8 qf = hi ? zf : *reinterpret_cast<const bf16x8*>(&qq[qrow * 64 + swz]);

        float sum = 0.f;
        f32x16 oacc = zero16();
        #pragma unroll
        for (int t = 0; t < 4; ++t) {            // sequential-tile: 1 st live
            f32x16 st = zero16();
            st = __builtin_amdgcn_mfma_f32_32x32x16_bf16(kf[t], qf, st, 0, 0, 0);
            #pragma unroll
            for (int r = 0; r < 16; ++r) { st[r] = fast_exp2(st[r]); sum += st[r]; }
            pvstep(st, vf[2 * t], vf[2 * t + 1], oacc);
        }
        sum += __shfl_xor(sum, 32);

        // O^T regs 0..3 hold d = 4*hi + reg for col n = qrow.
        const float inv = 1.0f / sum;
        uint2 u;
        u.x = cvt_pk_bf16(oacc[0] * inv, oacc[1] * inv);
        u.y = cvt_pk_bf16(oacc[2] * inv, oacc[3] * inv);
        *reinterpret_cast<uint2*>(&HS[(p0 + qrow) * 64 + h * 8 + hi * 4]) = u;
    }
}

// ---------------------------------------------------------------------------
// Kernel 2: temporal attention (causal + key padding), bf16 I/O.
// One block per (b, n); 192 threads = (head h, query time i).  (r13 version)
// ---------------------------------------------------------------------------
__global__ __launch_bounds__(192) void tattn_kernel(
    const unsigned short* __restrict__ Q, const unsigned short* __restrict__ Kb,
    const unsigned short* __restrict__ V, const int* __restrict__ kpm,
    unsigned short* __restrict__ O)
{
    __shared__ float kk[8][TT][8];
    __shared__ float vv[8][TT][8];
    const int tid = threadIdx.x;
    const int n = blockIdx.x & (NN - 1);
    const int b = blockIdx.x >> 7;

    {   // staging: thread = (head hs, time j): one 16-B bf16 load each for K and V
        const int hs = tid / TT;
        const int j  = tid % TT;
        const long g = (((long)(b * TT + j)) * NN + n) * 64 + hs * 8;
        uint4 ku = *reinterpret_cast<const uint4*>(&Kb[g]);
        uint4 vu = *reinterpret_cast<const uint4*>(&V[g]);
        float kf[8], vf[8];
        unpack8(ku, kf); unpack8(vu, vf);
        #pragma unroll
        for (int d = 0; d < 8; ++d) { kk[hs][j][d] = kf[d]; vv[hs][j][d] = vf[d]; }
    }

    const int h = tid / TT;
    const int i = tid % TT;
    const long qb = (((long)(b * TT + i)) * NN + n) * 64 + h * 8;
    float q[8];
    {
        uint4 qu = *reinterpret_cast<const uint4*>(&Q[qb]);
        unpack8(qu, q);
    }
    __syncthreads();

    const int kp = kpm[b];
    const float scale = 0.35355339059327373f;

    float s[TT];
    #pragma unroll
    for (int j = 0; j < TT; ++j) {
        float t = 0.0f;
        #pragma unroll
        for (int d = 0; d < 8; ++d) t = fmaf(q[d], kk[h][j][d], t);
        s[j] = (j <= i && j < kp) ? t * scale : -INFINITY;
    }
    float mx = -INFINITY;
    #pragma unroll
    for (int j = 0; j < TT; ++j) mx = fmaxf(mx, s[j]);

    float sum = 0.0f;
    float acc[8];
    #pragma unroll
    for (int d = 0; d < 8; ++d) acc[d] = 0.0f;
    #pragma unroll
    for (int j = 0; j < TT; ++j) {
        const float e = __expf(s[j] - mx);  // masked -> exp(-inf)=0
        sum += e;
        #pragma unroll
        for (int d = 0; d < 8; ++d) acc[d] = fmaf(e, vv[h][j][d], acc[d]);
    }
    const float inv = 1.0f / sum;
    float o[8];
    #pragma unroll
    for (int d = 0; d < 8; ++d) o[d] = acc[d] * inv;
    *reinterpret_cast<uint4*>(&O[qb]) = pack8(o);
}

// ---------------------------------------------------------------------------
// Kernel 3: epilogue via bf16 MFMA, swapped operands.
// r9 64-position structure + NEW: all 16 weight fragments built INLINE from
// the original fp32 matrices in the prologue (ef[8][2], compile-time
// indexed) -- removes the separate wprep kernel and the per-phase weight
// loads from the serial phase chain.
// Block = 256 thr (4 waves), 64-position tile.  Grid = PTOT/64 = 768.
// ---------------------------------------------------------------------------
__global__ __launch_bounds__(256) void epi_kernel(
    const float* __restrict__ X,
    const unsigned short* __restrict__ HSb, const unsigned short* __restrict__ HTb,
    const float* __restrict__ E0, const float* __restrict__ E1,
    const float* __restrict__ E2, const float* __restrict__ E3,
    const float* __restrict__ E4, const float* __restrict__ E5,
    const float* __restrict__ E6, const float* __restrict__ E7,
    const float* __restrict__ sbo1, const float* __restrict__ sbo2,
    const float* __restrict__ tbo1, const float* __restrict__ tbo2,
    const float* __restrict__ bxt,
    const float* __restrict__ bh1, const float* __restrict__ bh2,
    float* __restrict__ out)
{
    constexpr int RS = 72;
    __shared__ __align__(16) unsigned short bufA[64][RS], bufB[64][RS];
    __shared__ __align__(16) unsigned short bufC[64][RS], bufD[64][RS];
    const int tid = threadIdx.x;
    const long p0 = (long)blockIdx.x * 64;
    const int w = tid >> 6, l = tid & 63, quad = l >> 4, l16 = l & 15;
    const int chBase = w * 16 + quad * 4;

    // ---- build all 16 weight fragments inline (prologue; L2-resident) ----
    const float* Ep[8] = {E0, E1, E2, E3, E4, E5, E6, E7};
    bf16x8 ef[8][2];
    {
        const int n = w * 16 + l16;
        #pragma unroll
        for (int m = 0; m < 8; ++m)
            #pragma unroll
            for (int kc = 0; kc < 2; ++kc)
                ef[m][kc] = wfrag64(Ep[m], kc * 32 + quad * 8, n);
    }

    // ---- stage HS -> bufA, HT -> bufC (straight bf16 copy) ----
    #pragma unroll
    for (int i = 0; i < 4; ++i) {
        const int idx = tid + i * 256;      // < 1024
        const int m = idx >> 4;
        const int c = (idx & 15) * 4;
        *reinterpret_cast<ushort4*>(&bufA[m][c]) =
            *reinterpret_cast<const ushort4*>(&HSb[(p0 + m) * 64 + c]);
        *reinterpret_cast<ushort4*>(&bufC[m][c]) =
            *reinterpret_cast<const ushort4*>(&HTb[(p0 + m) * 64 + c]);
    }
    __syncthreads();

    auto gemm = [&](const unsigned short (*in)[RS], const bf16x8* af,
                    const float* __restrict__ bias, f32x4* accO) {
        const float4 b4 = *reinterpret_cast<const float4*>(&bias[chBase]);
        #pragma unroll
        for (int pt = 0; pt < 4; ++pt) {
            f32x4 acc = (f32x4){b4.x, b4.y, b4.z, b4.w};   // bias in C
            #pragma unroll
            for (int kc = 0; kc < 2; ++kc) {
                bf16x8 bf = *reinterpret_cast<const bf16x8*>(
                    &in[pt * 16 + l16][kc * 32 + quad * 8]);
                acc = __builtin_amdgcn_mfma_f32_16x16x32_bf16(af[kc], bf, acc, 0, 0, 0);
            }
            accO[pt] = acc;
        }
    };

    auto writeBuf = [&](unsigned short (*dst)[RS], const f32x4* v, bool relu) {
        #pragma unroll
        for (int pt = 0; pt < 4; ++pt) {
            float a0 = v[pt][0], a1 = v[pt][1], a2 = v[pt][2], a3 = v[pt][3];
            if (relu) { a0 = fmaxf(a0, 0.f); a1 = fmaxf(a1, 0.f);
                        a2 = fmaxf(a2, 0.f); a3 = fmaxf(a3, 0.f); }
            uint2 u;
            u.x = cvt_pk_bf16(a0, a1);
            u.y = cvt_pk_bf16(a2, a3);
            *reinterpret_cast<uint2*>(&dst[pt * 16 + l16][chBase]) = u;
        }
    };

    f32x4 tS[4], tT[4], HSr[4], HTr[4];

    // P1: HS1 and HT1 in one phase
    gemm(bufA, ef[0], sbo1, tS);
    gemm(bufC, ef[2], tbo1, tT);
    __syncthreads();
    writeBuf(bufB, tS, true);
    writeBuf(bufD, tT, true);
    __syncthreads();

    // P2: HS2 and HT2 in one phase
    gemm(bufB, ef[1], sbo2, HSr);
    gemm(bufD, ef[3], tbo2, HTr);
    __syncthreads();
    writeBuf(bufA, HSr, false);
    writeBuf(bufC, HTr, false);
    __syncthreads();

    // P3: gate
    {
        const float4 b4 = *reinterpret_cast<const float4*>(&bxt[chBase]);
        #pragma unroll
        for (int pt = 0; pt < 4; ++pt) {
            f32x4 acc = (f32x4){b4.x, b4.y, b4.z, b4.w};   // bias in C
            #pragma unroll
            for (int kc = 0; kc < 2; ++kc) {
                bf16x8 hsf = *reinterpret_cast<const bf16x8*>(
                    &bufA[pt * 16 + l16][kc * 32 + quad * 8]);
                acc = __builtin_amdgcn_mfma_f32_16x16x32_bf16(ef[4][kc], hsf, acc, 0, 0, 0);
            }
            #pragma unroll
            for (int kc = 0; kc < 2; ++kc) {
                bf16x8 htf = *reinterpret_cast<const bf16x8*>(
                    &bufC[pt * 16 + l16][kc * 32 + quad * 8]);
                acc = __builtin_amdgcn_mfma_f32_16x16x32_bf16(ef[5][kc], htf, acc, 0, 0, 0);
            }
            f32x4 h;
            #pragma unroll
            for (int r = 0; r < 4; ++r) {
                const float z = 1.0f / (1.0f + __expf(-acc[r]));
                h[r] = z * HSr[pt][r] + (1.0f - z) * HTr[pt][r];
            }
            tS[pt] = h;
        }
    }
    // bufB free since P2's gemm (>=1 barrier ago) -> write without extra bar
    writeBuf(bufB, tS, false);
    __syncthreads();

    // P4: H1 = relu(H@Wh1+b)
    gemm(bufB, ef[6], bh1, tS);
    __syncthreads();
    writeBuf(bufA, tS, true);
    __syncthreads();

    // P5: out = X + H1@Wh2+b
    gemm(bufA, ef[7], bh2, tS);
    #pragma unroll
    for (int pt = 0; pt < 4; ++pt) {
        const long pos = p0 + pt * 16 + l16;
        const float4 xv = *reinterpret_cast<const float4*>(&X[pos * 64 + chBase]);
        float4 o;
        o.x = tS[pt][0] + xv.x; o.y = tS[pt][1] + xv.y;
        o.z = tS[pt][2] + xv.z; o.w = tS[pt][3] + xv.w;
        *reinterpret_cast<float4*>(&out[pos * 64 + chBase]) = o;
    }
}

// ---------------------------------------------------------------------------
extern "C" void kernel_launch(void* const* d_in, const int* in_sizes, int n_in,
                              void* d_out, int out_size, void* d_ws, size_t ws_size,
                              hipStream_t stream) {
    const float* X   = (const float*)d_in[0];
    const float* TLE = (const float*)d_in[1];
    const int* kpm   = (const int*)d_in[2];

    const float* sa_Wq = (const float*)d_in[3];  const float* sa_bq = (const float*)d_in[4];
    const float* sa_Wk = (const float*)d_in[5];  const float* sa_bk = (const float*)d_in[6];
    const float* sa_Wv = (const float*)d_in[7];  const float* sa_bv = (const float*)d_in[8];
    const float* sa_Wo1 = (const float*)d_in[9];  const float* sa_bo1 = (const float*)d_in[10];
    const float* sa_Wo2 = (const float*)d_in[11]; const float* sa_bo2 = (const float*)d_in[12];
    const float* ta_Wq = (const float*)d_in[13]; const float* ta_bq = (const float*)d_in[14];
    const float* ta_Wk = (const float*)d_in[15]; const float* ta_bk = (const float*)d_in[16];
    const float* ta_Wv = (const float*)d_in[17]; const float* ta_bv = (const float*)d_in[18];
    const float* ta_Wo1 = (const float*)d_in[19]; const float* ta_bo1 = (const float*)d_in[20];
    const float* ta_Wo2 = (const float*)d_in[21]; const float* ta_bo2 = (const float*)d_in[22];
    const float* g_Wxs = (const float*)d_in[23];
    const float* g_Wxt = (const float*)d_in[24]; const float* g_bxt = (const float*)d_in[25];
    const float* g_Wh1 = (const float*)d_in[26]; const float* g_bh1 = (const float*)d_in[27];
    const float* g_Wh2 = (const float*)d_in[28]; const float* g_bh2 = (const float*)d_in[29];

    unsigned short* wsp = (unsigned short*)d_ws;
    unsigned short* qt  = wsp + 0L * P64;
    unsigned short* kt  = wsp + 1L * P64;
    unsigned short* vt  = wsp + 2L * P64;
    unsigned short* HSb = wsp + 3L * P64;
    unsigned short* HTb = wsp + 4L * P64;

    float* out = (float*)d_out;

    hipLaunchKernelGGL(fused_sattn, dim3(BB * TT), dim3(512), 0, stream,
                       X, TLE,
                       sa_Wq, sa_Wk, sa_Wv, ta_Wq, ta_Wk, ta_Wv,
                       sa_bq, sa_bk, sa_bv, ta_bq, ta_bk, ta_bv,
                       qt, kt, vt, HSb);

    hipLaunchKernelGGL(tattn_kernel, dim3(BB * NN), dim3(192), 0, stream,
                       qt, kt, vt, kpm, HTb);

    hipLaunchKernelGGL(epi_kernel, dim3(PTOT / 64), dim3(256), 0, stream,
                       X, HSb, HTb,
                       sa_Wo1, sa_Wo2, ta_Wo1, ta_Wo2, g_Wxs, g_Wxt, g_Wh1, g_Wh2,
                       sa_bo1, sa_bo2, ta_bo1, ta_bo2, g_bxt, g_bh1, g_bh2,
                       out);
}

// Round 19
// 69.113 us; speedup vs baseline: 1.1643x; 1.1643x over previous
//
#include <hip/hip_runtime.h>
#include <math.h>

#define BB 16
#define TT 24
#define NN 128
#define DD 64
#define PTOT (BB * TT * NN)   // 49152 positions
#define P64  (PTOT * 64)      // elements per (B,T,N,64) buffer

typedef __attribute__((ext_vector_type(8))) short bf16x8;
typedef __attribute__((ext_vector_type(4))) float f32x4;
typedef __attribute__((ext_vector_type(16))) float f32x16;

__device__ __forceinline__ unsigned short f2bf(float f) {
    unsigned u = __builtin_bit_cast(unsigned, f);
    u = (u + 0x7fffu + ((u >> 16) & 1u)) >> 16;   // round-to-nearest-even
    return (unsigned short)u;
}
__device__ __forceinline__ unsigned cvt_pk_bf16(float a, float b) {
    unsigned r;
    asm("v_cvt_pk_bf16_f32 %0, %1, %2" : "=v"(r) : "v"(a), "v"(b));
    return r;   // low16 = bf16(a), high16 = bf16(b)
}
__device__ __forceinline__ void unpack8(uint4 u, float* f) {
    f[0] = __builtin_bit_cast(float, u.x << 16);
    f[1] = __builtin_bit_cast(float, u.x & 0xFFFF0000u);
    f[2] = __builtin_bit_cast(float, u.y << 16);
    f[3] = __builtin_bit_cast(float, u.y & 0xFFFF0000u);
    f[4] = __builtin_bit_cast(float, u.z << 16);
    f[5] = __builtin_bit_cast(float, u.z & 0xFFFF0000u);
    f[6] = __builtin_bit_cast(float, u.w << 16);
    f[7] = __builtin_bit_cast(float, u.w & 0xFFFF0000u);
}
__device__ __forceinline__ uint4 pack8(const float* f) {
    uint4 o;
    o.x = cvt_pk_bf16(f[0], f[1]);
    o.y = cvt_pk_bf16(f[2], f[3]);
    o.z = cvt_pk_bf16(f[4], f[5]);
    o.w = cvt_pk_bf16(f[6], f[7]);
    return o;
}
__device__ __forceinline__ float fast_exp2(float x) {
#if __has_builtin(__builtin_amdgcn_exp2f)
    return __builtin_amdgcn_exp2f(x);
#else
    return exp2f(x);
#endif
}
__device__ __forceinline__ f32x16 zero16() {
    f32x16 z;
    #pragma unroll
    for (int i = 0; i < 16; ++i) z[i] = 0.f;
    return z;
}

// ---------------------------------------------------------------------------
// Kernel 0: combined weight prep.
// blocks 0..287: 6 proj weights (192x64) -> bf16 [j][n][k]  (Wt)
// blocks 288..415: 8 epi weights (64x64) -> bf16 [mat][n][k] (Wt8)
// ---------------------------------------------------------------------------
__global__ __launch_bounds__(256) void wprep_all(
    const float* __restrict__ W0, const float* __restrict__ W1,
    const float* __restrict__ W2, const float* __restrict__ W3,
    const float* __restrict__ W4, const float* __restrict__ W5,
    const float* __restrict__ E0, const float* __restrict__ E1,
    const float* __restrict__ E2, const float* __restrict__ E3,
    const float* __restrict__ E4, const float* __restrict__ E5,
    const float* __restrict__ E6, const float* __restrict__ E7,
    unsigned short* __restrict__ Wt, unsigned short* __restrict__ Wt8)
{
    const int bid = blockIdx.x;
    if (bid < 288) {
        const float* Ws[6] = {W0, W1, W2, W3, W4, W5};
        const int e = bid * 256 + threadIdx.x;          // < 73728
        const int j = e / 12288;
        const int r = e % 12288;
        const int k = r / 64;
        const int n = r % 64;
        Wt[j * 12288 + n * 192 + k] = f2bf(Ws[j][k * 64 + n]);
    } else {
        const float* Es[8] = {E0, E1, E2, E3, E4, E5, E6, E7};
        const int e = (bid - 288) * 256 + threadIdx.x;  // < 32768
        const int mat = e >> 12;
        const int r = e & 4095;
        const int k = r >> 6;
        const int n = r & 63;
        Wt8[mat * 4096 + n * 64 + k] = f2bf(Es[mat][k * 64 + n]);
    }
}

// ---------------------------------------------------------------------------
// Kernel 1: FUSED 6-way QKV projection + MFMA spatial attention.
// BEST configuration (69.2us total, round-14 bench): spill-free 8-deep
// named-register staging + transposed-V LDS. No setprio, no macro-tiling,
// no inline wprep (all probed null/negative r15-r18).
// One block per (b,t): 128 positions, 512 threads (8 waves).
//   GEMM: wave w -> ch-tile nt=w>>1, mats mg=(w&1)*3+{0,1,2}; cvt_pk
//         packing; bias in MFMA C-operand; temporal q/k/v pos-major.
//   Attention: wave w -> head w; S^T=mfma(K,Q), sequential-tile softmax,
//         in-register P repack, O^T=mfma(V^T,P^T); V^T via ds_read_b128
//         from transposed-swizzled vvT.
// Barriers: relaxed lgkmcnt-only per mt. LDS: 61,952 B. bounds(512,2).
// ---------------------------------------------------------------------------
__global__ __launch_bounds__(512, 2) void fused_sattn(
    const float* __restrict__ X, const float* __restrict__ TLE,
    const unsigned short* __restrict__ Wt,   // [6][64][192] bf16
    const float* __restrict__ b0, const float* __restrict__ b1,
    const float* __restrict__ b2, const float* __restrict__ b3,
    const float* __restrict__ b4, const float* __restrict__ b5,
    unsigned short* __restrict__ qt, unsigned short* __restrict__ kt,
    unsigned short* __restrict__ vt,
    unsigned short* __restrict__ HS)
{
    __shared__ __align__(16) unsigned short xe[2][16][200];   // staged XE tile
    __shared__ __align__(16) unsigned short qq[128 * 64];     // swizzled bf16
    __shared__ __align__(16) unsigned short kk[128 * 64];
    __shared__ __align__(16) unsigned short vvT[64 * 128];    // V transposed
    const int tid = threadIdx.x;
    const long p0 = (long)blockIdx.x * 128;
    const int w = tid >> 6, l = tid & 63, quad = l >> 4, l16 = l & 15;
    const int nt = w >> 1;               // channel tile 0..3
    const int mg = (w & 1) * 3;          // 0 = spatial q/k/v, 3 = temporal

    // ---- per-thread staging geometry (same for every tile) ----
    int mj[3], kj[3];
    const float* srcb[3];   // tile-0 source address; tile t adds row stride
    long rstride[3];        // floats to advance per tile (16 rows)
    #pragma unroll
    for (int j = 0; j < 3; ++j) {
        const int f = (j * 512 + tid) * 2;
        mj[j] = f / 192;
        kj[j] = f % 192;
        if (kj[j] < 64) { srcb[j] = X + (p0 + mj[j]) * 64 + kj[j];  rstride[j] = 16 * 64; }
        else            { srcb[j] = TLE + (p0 + mj[j]) * 128 + (kj[j] - 64); rstride[j] = 16 * 128; }
    }

    // ---- 8-deep staging in NAMED registers (no array -> no scratch) ----
    uint2 t0a, t0b, t0c, t1a, t1b, t1c, t2a, t2b, t2c, t3a, t3b, t3c,
          t4a, t4b, t4c, t5a, t5b, t5c, t6a, t6b, t6c, t7a, t7b, t7c;
#define LOADT(T, A, B, C) \
    A = *reinterpret_cast<const uint2*>(srcb[0] + (long)(T) * rstride[0]); \
    B = *reinterpret_cast<const uint2*>(srcb[1] + (long)(T) * rstride[1]); \
    C = *reinterpret_cast<const uint2*>(srcb[2] + (long)(T) * rstride[2]);
    LOADT(0, t0a, t0b, t0c)
    LOADT(1, t1a, t1b, t1c)
    LOADT(2, t2a, t2b, t2c)
    LOADT(3, t3a, t3b, t3c)
    LOADT(4, t4a, t4b, t4c)
    LOADT(5, t5a, t5b, t5c)
    LOADT(6, t6a, t6b, t6c)
    LOADT(7, t7a, t7b, t7c)
#undef LOADT

    // staging write from registers (by value -> always register operands)
    auto swr = [&](uint2 a, uint2 b, uint2 c, int buf) {
        *reinterpret_cast<unsigned*>(&xe[buf][mj[0]][kj[0]]) =
            cvt_pk_bf16(__builtin_bit_cast(float, a.x), __builtin_bit_cast(float, a.y));
        *reinterpret_cast<unsigned*>(&xe[buf][mj[1]][kj[1]]) =
            cvt_pk_bf16(__builtin_bit_cast(float, b.x), __builtin_bit_cast(float, b.y));
        *reinterpret_cast<unsigned*>(&xe[buf][mj[2]][kj[2]]) =
            cvt_pk_bf16(__builtin_bit_cast(float, c.x), __builtin_bit_cast(float, c.y));
    };

    // ---- preload this wave's 18 weight fragments (ch rows = nt*16+l16) ----
    bf16x8 wf[3][6];
    #pragma unroll
    for (int mi = 0; mi < 3; ++mi)
        #pragma unroll
        for (int kc = 0; kc < 6; ++kc)
            wf[mi][kc] = *reinterpret_cast<const bf16x8*>(
                &Wt[(mg + mi) * 12288 + (nt * 16 + l16) * 192 + kc * 32 + quad * 8]);

    const float* bias_p[6] = {b0, b1, b2, b3, b4, b5};
    float4 bias[3];
    #pragma unroll
    for (int mi = 0; mi < 3; ++mi)
        bias[mi] = *reinterpret_cast<const float4*>(&bias_p[mg + mi][nt * 16 + quad * 4]);

    swr(t0a, t0b, t0c, 0);
    __syncthreads();

    const int chBase = nt * 16 + quad * 4;          // channel base
    const int chunkW = nt * 2 + (quad >> 1);        // 8-ch chunk (q/k LDS)
    const int chSub  = (quad & 1) * 4;              // offset within chunk
    const float cs = 0.35355339059327373f * 1.4426950408889634f;  // scale*log2e

    #pragma unroll
    for (int mt = 0; mt < 8; ++mt) {
        switch (mt) {                                // stage tile mt+1 (literal)
            case 0: swr(t1a, t1b, t1c, 1); break;
            case 1: swr(t2a, t2b, t2c, 0); break;
            case 2: swr(t3a, t3b, t3c, 1); break;
            case 3: swr(t4a, t4b, t4c, 0); break;
            case 4: swr(t5a, t5b, t5c, 1); break;
            case 5: swr(t6a, t6b, t6c, 0); break;
            case 6: swr(t7a, t7b, t7c, 1); break;
            default: break;
        }

        bf16x8 A[6];
        #pragma unroll
        for (int kc = 0; kc < 6; ++kc)
            A[kc] = *reinterpret_cast<const bf16x8*>(
                &xe[mt & 1][l16][kc * 32 + quad * 8]);

        // bias folded into accumulator init (C operand of MFMA)
        f32x4 acc[3];
        #pragma unroll
        for (int mi = 0; mi < 3; ++mi)
            acc[mi] = (f32x4){bias[mi].x, bias[mi].y, bias[mi].z, bias[mi].w};
        #pragma unroll
        for (int kc = 0; kc < 6; ++kc)
            #pragma unroll
            for (int mi = 0; mi < 3; ++mi)
                acc[mi] = __builtin_amdgcn_mfma_f32_16x16x32_bf16(
                    wf[mi][kc], A[kc], acc[mi], 0, 0, 0);

        const int pos = mt * 16 + l16;              // lane's position (C/D col)
        if (mg == 0) {                              // spatial -> LDS
            const int sw = pos * 64 + ((chunkW ^ (pos & 7)) << 3) + chSub;
            uint2 uq;
            uq.x = cvt_pk_bf16(fmaxf(acc[0][0], 0.f) * cs, fmaxf(acc[0][1], 0.f) * cs);
            uq.y = cvt_pk_bf16(fmaxf(acc[0][2], 0.f) * cs, fmaxf(acc[0][3], 0.f) * cs);
            *reinterpret_cast<uint2*>(&qq[sw]) = uq;
            uint2 uk;
            uk.x = cvt_pk_bf16(fmaxf(acc[1][0], 0.f), fmaxf(acc[1][1], 0.f));
            uk.y = cvt_pk_bf16(fmaxf(acc[1][2], 0.f), fmaxf(acc[1][3], 0.f));
            *reinterpret_cast<uint2*>(&kk[sw]) = uk;
            // V -> TRANSPOSED LDS: vvT[ch*128 + (pos ^ ((ch&7)<<3))]
            const unsigned pv0 = cvt_pk_bf16(fmaxf(acc[2][0], 0.f), fmaxf(acc[2][1], 0.f));
            const unsigned pv1 = cvt_pk_bf16(fmaxf(acc[2][2], 0.f), fmaxf(acc[2][3], 0.f));
            vvT[(chBase + 0) * 128 + (pos ^ (((chBase + 0) & 7) << 3))] = (unsigned short)pv0;
            vvT[(chBase + 1) * 128 + (pos ^ (((chBase + 1) & 7) << 3))] = (unsigned short)(pv0 >> 16);
            vvT[(chBase + 2) * 128 + (pos ^ (((chBase + 2) & 7) << 3))] = (unsigned short)pv1;
            vvT[(chBase + 3) * 128 + (pos ^ (((chBase + 3) & 7) << 3))] = (unsigned short)(pv1 >> 16);
        } else {                                    // temporal -> global bf16
            unsigned short* dstT[3] = {qt, kt, vt};
            const long gp = (p0 + pos) * 64 + chBase;
            #pragma unroll
            for (int mi = 0; mi < 3; ++mi) {
                uint2 u;
                u.x = cvt_pk_bf16(fmaxf(acc[mi][0], 0.f), fmaxf(acc[mi][1], 0.f));
                u.y = cvt_pk_bf16(fmaxf(acc[mi][2], 0.f), fmaxf(acc[mi][3], 0.f));
                *reinterpret_cast<uint2*>(&dstT[mi][gp]) = u;
            }
        }
        // LDS-only barrier (no vmcnt drain of the temporal stores).
        __builtin_amdgcn_sched_barrier(0);
        asm volatile("s_waitcnt lgkmcnt(0)" ::: "memory");
        __builtin_amdgcn_s_barrier();
        __builtin_amdgcn_sched_barrier(0);
    }
    // (the mt==7 pass of the barrier above is the inter-phase barrier)

    // ---------------- MFMA attention phase: wave w == head w ----------------
    const int h  = w;
    const int hi = l >> 5;            // lane half (0/1)
    const int ln = l & 31;            // lane-in-half
    bf16x8 zf = {};
    const int swz = (h ^ (ln & 7)) << 3;

    // P^T-tile -> PV B-frag repack + 2 PV MFMAs.
    auto pvstep = [&](f32x16& st, const bf16x8& va0, const bf16x8& va1,
                      f32x16& oacc) {
        const unsigned P0 = cvt_pk_bf16(st[0],  st[1]);
        const unsigned P1 = cvt_pk_bf16(st[2],  st[3]);
        const unsigned P2 = cvt_pk_bf16(st[4],  st[5]);
        const unsigned P3 = cvt_pk_bf16(st[6],  st[7]);
        const unsigned P4 = cvt_pk_bf16(st[8],  st[9]);
        const unsigned P5 = cvt_pk_bf16(st[10], st[11]);
        const unsigned P6 = cvt_pk_bf16(st[12], st[13]);
        const unsigned P7 = cvt_pk_bf16(st[14], st[15]);
        const unsigned V0 = __shfl_xor(hi ? P0 : P2, 32);
        const unsigned V1 = __shfl_xor(hi ? P1 : P3, 32);
        const unsigned V2 = __shfl_xor(hi ? P4 : P6, 32);
        const unsigned V3 = __shfl_xor(hi ? P5 : P7, 32);
        uint4 fe, fo;
        fe.x = hi ? V0 : P0; fe.y = hi ? V1 : P1;
        fe.z = hi ? P2 : V0; fe.w = hi ? P3 : V1;
        fo.x = hi ? V2 : P4; fo.y = hi ? V3 : P5;
        fo.z = hi ? P6 : V2; fo.w = hi ? P7 : V3;
        oacc = __builtin_amdgcn_mfma_f32_32x32x16_bf16(
            va0, __builtin_bit_cast(bf16x8, fe), oacc, 0, 0, 0);
        oacc = __builtin_amdgcn_mfma_f32_32x32x16_bf16(
            va1, __builtin_bit_cast(bf16x8, fo), oacc, 0, 0, 0);
    };

    // K A-frags (4 m-tiles): lane ln holds K[row=t*32+ln][d=hi*8+j];
    // hi=1 half is the d=8..15 zero padding.
    bf16x8 kf[4];
    #pragma unroll
    for (int t = 0; t < 4; ++t)
        kf[t] = hi ? zf : *reinterpret_cast<const bf16x8*>(&kk[(t * 32 + ln) * 64 + swz]);

    // V^T A-frags (8 m-chunks): lane ln<8 = dim d; one ds_read_b128 each
    // (8 contiguous swizzled positions), rows d>=8 zero.
    bf16x8 vf[8];
    #pragma unroll
    for (int c = 0; c < 8; ++c) {
        bf16x8 f = zf;
        if (ln < 8) {
            const int base = (h * 8 + ln) * 128 + ((c * 16 + hi * 8) ^ (ln << 3));
            f = *reinterpret_cast<const bf16x8*>(&vvT[base]);
        }
        vf[c] = f;
    }

    #pragma unroll
    for (int ntq = 0; ntq < 4; ++ntq) {
        const int qrow = ntq * 32 + ln;
        bf16x8 qf = hi ? zf : *reinterpret_cast<const bf16x8*>(&qq[qrow * 64 + swz]);

        float sum = 0.f;
        f32x16 oacc = zero16();
        #pragma unroll
        for (int t = 0; t < 4; ++t) {            // sequential-tile: 1 st live
            f32x16 st = zero16();
            st = __builtin_amdgcn_mfma_f32_32x32x16_bf16(kf[t], qf, st, 0, 0, 0);
            #pragma unroll
            for (int r = 0; r < 16; ++r) { st[r] = fast_exp2(st[r]); sum += st[r]; }
            pvstep(st, vf[2 * t], vf[2 * t + 1], oacc);
        }
        sum += __shfl_xor(sum, 32);

        // O^T regs 0..3 hold d = 4*hi + reg for col n = qrow.
        const float inv = 1.0f / sum;
        uint2 u;
        u.x = cvt_pk_bf16(oacc[0] * inv, oacc[1] * inv);
        u.y = cvt_pk_bf16(oacc[2] * inv, oacc[3] * inv);
        *reinterpret_cast<uint2*>(&HS[(p0 + qrow) * 64 + h * 8 + hi * 4]) = u;
    }
}

// ---------------------------------------------------------------------------
// Kernel 2: temporal attention (causal + key padding), bf16 I/O.
// One block per (b, n); 192 threads = (head h, query time i).
// ---------------------------------------------------------------------------
__global__ __launch_bounds__(192) void tattn_kernel(
    const unsigned short* __restrict__ Q, const unsigned short* __restrict__ Kb,
    const unsigned short* __restrict__ V, const int* __restrict__ kpm,
    unsigned short* __restrict__ O)
{
    __shared__ float kk[8][TT][8];
    __shared__ float vv[8][TT][8];
    const int tid = threadIdx.x;
    const int n = blockIdx.x & (NN - 1);
    const int b = blockIdx.x >> 7;

    {   // staging: thread = (head hs, time j): one 16-B bf16 load each for K and V
        const int hs = tid / TT;
        const int j  = tid % TT;
        const long g = (((long)(b * TT + j)) * NN + n) * 64 + hs * 8;
        uint4 ku = *reinterpret_cast<const uint4*>(&Kb[g]);
        uint4 vu = *reinterpret_cast<const uint4*>(&V[g]);
        float kf[8], vf[8];
        unpack8(ku, kf); unpack8(vu, vf);
        #pragma unroll
        for (int d = 0; d < 8; ++d) { kk[hs][j][d] = kf[d]; vv[hs][j][d] = vf[d]; }
    }

    const int h = tid / TT;
    const int i = tid % TT;
    const long qb = (((long)(b * TT + i)) * NN + n) * 64 + h * 8;
    float q[8];
    {
        uint4 qu = *reinterpret_cast<const uint4*>(&Q[qb]);
        unpack8(qu, q);
    }
    __syncthreads();

    const int kp = kpm[b];
    const float scale = 0.35355339059327373f;

    float s[TT];
    #pragma unroll
    for (int j = 0; j < TT; ++j) {
        float t = 0.0f;
        #pragma unroll
        for (int d = 0; d < 8; ++d) t = fmaf(q[d], kk[h][j][d], t);
        s[j] = (j <= i && j < kp) ? t * scale : -INFINITY;
    }
    float mx = -INFINITY;
    #pragma unroll
    for (int j = 0; j < TT; ++j) mx = fmaxf(mx, s[j]);

    float sum = 0.0f;
    float acc[8];
    #pragma unroll
    for (int d = 0; d < 8; ++d) acc[d] = 0.0f;
    #pragma unroll
    for (int j = 0; j < TT; ++j) {
        const float e = __expf(s[j] - mx);  // masked -> exp(-inf)=0
        sum += e;
        #pragma unroll
        for (int d = 0; d < 8; ++d) acc[d] = fmaf(e, vv[h][j][d], acc[d]);
    }
    const float inv = 1.0f / sum;
    float o[8];
    #pragma unroll
    for (int d = 0; d < 8; ++d) o[d] = acc[d] * inv;
    *reinterpret_cast<uint4*>(&O[qb]) = pack8(o);
}

// ---------------------------------------------------------------------------
// Kernel 3: epilogue via bf16 MFMA, swapped operands.
// Block = 256 thr (4 waves), 64-position tile.  Grid = PTOT/64 = 768.
// Phase-paired HS/HT chains; bias in C; cvt_pk packing.
// ---------------------------------------------------------------------------
__global__ __launch_bounds__(256) void epi_kernel(
    const float* __restrict__ X,
    const unsigned short* __restrict__ HSb, const unsigned short* __restrict__ HTb,
    const unsigned short* __restrict__ Wt8,  // [8][64][64] bf16
    const float* __restrict__ sbo1, const float* __restrict__ sbo2,
    const float* __restrict__ tbo1, const float* __restrict__ tbo2,
    const float* __restrict__ bxt,
    const float* __restrict__ bh1, const float* __restrict__ bh2,
    float* __restrict__ out)
{
    constexpr int RS = 72;
    __shared__ __align__(16) unsigned short bufA[64][RS], bufB[64][RS];
    __shared__ __align__(16) unsigned short bufC[64][RS], bufD[64][RS];
    const int tid = threadIdx.x;
    const long p0 = (long)blockIdx.x * 64;
    const int w = tid >> 6, l = tid & 63, quad = l >> 4, l16 = l & 15;
    const int chBase = w * 16 + quad * 4;

    // ---- stage HS -> bufA, HT -> bufC (straight bf16 copy) ----
    #pragma unroll
    for (int i = 0; i < 4; ++i) {
        const int idx = tid + i * 256;      // < 1024
        const int m = idx >> 4;
        const int c = (idx & 15) * 4;
        *reinterpret_cast<ushort4*>(&bufA[m][c]) =
            *reinterpret_cast<const ushort4*>(&HSb[(p0 + m) * 64 + c]);
        *reinterpret_cast<ushort4*>(&bufC[m][c]) =
            *reinterpret_cast<const ushort4*>(&HTb[(p0 + m) * 64 + c]);
    }
    __syncthreads();

    auto gemm = [&](const unsigned short (*in)[RS], int mat,
                    const float* __restrict__ bias, f32x4* accO) {
        bf16x8 af[2];
        #pragma unroll
        for (int kc = 0; kc < 2; ++kc)
            af[kc] = *reinterpret_cast<const bf16x8*>(
                &Wt8[mat * 4096 + (w * 16 + l16) * 64 + kc * 32 + quad * 8]);
        const float4 b4 = *reinterpret_cast<const float4*>(&bias[chBase]);
        #pragma unroll
        for (int pt = 0; pt < 4; ++pt) {
            f32x4 acc = (f32x4){b4.x, b4.y, b4.z, b4.w};   // bias in C
            #pragma unroll
            for (int kc = 0; kc < 2; ++kc) {
                bf16x8 bf = *reinterpret_cast<const bf16x8*>(
                    &in[pt * 16 + l16][kc * 32 + quad * 8]);
                acc = __builtin_amdgcn_mfma_f32_16x16x32_bf16(af[kc], bf, acc, 0, 0, 0);
            }
            accO[pt] = acc;
        }
    };

    auto writeBuf = [&](unsigned short (*dst)[RS], const f32x4* v, bool relu) {
        #pragma unroll
        for (int pt = 0; pt < 4; ++pt) {
            float a0 = v[pt][0], a1 = v[pt][1], a2 = v[pt][2], a3 = v[pt][3];
            if (relu) { a0 = fmaxf(a0, 0.f); a1 = fmaxf(a1, 0.f);
                        a2 = fmaxf(a2, 0.f); a3 = fmaxf(a3, 0.f); }
            uint2 u;
            u.x = cvt_pk_bf16(a0, a1);
            u.y = cvt_pk_bf16(a2, a3);
            *reinterpret_cast<uint2*>(&dst[pt * 16 + l16][chBase]) = u;
        }
    };

    f32x4 tS[4], tT[4], HSr[4], HTr[4];

    // P1: HS1 and HT1 in one phase
    gemm(bufA, 0, sbo1, tS);
    gemm(bufC, 2, tbo1, tT);
    __syncthreads();
    writeBuf(bufB, tS, true);
    writeBuf(bufD, tT, true);
    __syncthreads();

    // P2: HS2 and HT2 in one phase
    gemm(bufB, 1, sbo2, HSr);
    gemm(bufD, 3, tbo2, HTr);
    __syncthreads();
    writeBuf(bufA, HSr, false);
    writeBuf(bufC, HTr, false);
    __syncthreads();

    // P3: gate
    {
        bf16x8 afS[2], afT[2];
        #pragma unroll
        for (int kc = 0; kc < 2; ++kc) {
            afS[kc] = *reinterpret_cast<const bf16x8*>(
                &Wt8[4 * 4096 + (w * 16 + l16) * 64 + kc * 32 + quad * 8]);
            afT[kc] = *reinterpret_cast<const bf16x8*>(
                &Wt8[5 * 4096 + (w * 16 + l16) * 64 + kc * 32 + quad * 8]);
        }
        const float4 b4 = *reinterpret_cast<const float4*>(&bxt[chBase]);
        #pragma unroll
        for (int pt = 0; pt < 4; ++pt) {
            f32x4 acc = (f32x4){b4.x, b4.y, b4.z, b4.w};   // bias in C
            #pragma unroll
            for (int kc = 0; kc < 2; ++kc) {
                bf16x8 hsf = *reinterpret_cast<const bf16x8*>(
                    &bufA[pt * 16 + l16][kc * 32 + quad * 8]);
                acc = __builtin_amdgcn_mfma_f32_16x16x32_bf16(afS[kc], hsf, acc, 0, 0, 0);
            }
            #pragma unroll
            for (int kc = 0; kc < 2; ++kc) {
                bf16x8 htf = *reinterpret_cast<const bf16x8*>(
                    &bufC[pt * 16 + l16][kc * 32 + quad * 8]);
                acc = __builtin_amdgcn_mfma_f32_16x16x32_bf16(afT[kc], htf, acc, 0, 0, 0);
            }
            f32x4 h;
            #pragma unroll
            for (int r = 0; r < 4; ++r) {
                const float z = 1.0f / (1.0f + __expf(-acc[r]));
                h[r] = z * HSr[pt][r] + (1.0f - z) * HTr[pt][r];
            }
            tS[pt] = h;
        }
    }
    // bufB free since P2's gemm (>=1 barrier ago) -> write without extra bar
    writeBuf(bufB, tS, false);
    __syncthreads();

    // P4: H1 = relu(H@Wh1+b)
    gemm(bufB, 6, bh1, tS);
    __syncthreads();
    writeBuf(bufA, tS, true);
    __syncthreads();

    // P5: out = X + H1@Wh2+b
    gemm(bufA, 7, bh2, tS);
    #pragma unroll
    for (int pt = 0; pt < 4; ++pt) {
        const long pos = p0 + pt * 16 + l16;
        const float4 xv = *reinterpret_cast<const float4*>(&X[pos * 64 + chBase]);
        float4 o;
        o.x = tS[pt][0] + xv.x; o.y = tS[pt][1] + xv.y;
        o.z = tS[pt][2] + xv.z; o.w = tS[pt][3] + xv.w;
        *reinterpret_cast<float4*>(&out[pos * 64 + chBase]) = o;
    }
}

// ---------------------------------------------------------------------------
extern "C" void kernel_launch(void* const* d_in, const int* in_sizes, int n_in,
                              void* d_out, int out_size, void* d_ws, size_t ws_size,
                              hipStream_t stream) {
    const float* X   = (const float*)d_in[0];
    const float* TLE = (const float*)d_in[1];
    const int* kpm   = (const int*)d_in[2];

    const float* sa_Wq = (const float*)d_in[3];  const float* sa_bq = (const float*)d_in[4];
    const float* sa_Wk = (const float*)d_in[5];  const float* sa_bk = (const float*)d_in[6];
    const float* sa_Wv = (const float*)d_in[7];  const float* sa_bv = (const float*)d_in[8];
    const float* sa_Wo1 = (const float*)d_in[9];  const float* sa_bo1 = (const float*)d_in[10];
    const float* sa_Wo2 = (const float*)d_in[11]; const float* sa_bo2 = (const float*)d_in[12];
    const float* ta_Wq = (const float*)d_in[13]; const float* ta_bq = (const float*)d_in[14];
    const float* ta_Wk = (const float*)d_in[15]; const float* ta_bk = (const float*)d_in[16];
    const float* ta_Wv = (const float*)d_in[17]; const float* ta_bv = (const float*)d_in[18];
    const float* ta_Wo1 = (const float*)d_in[19]; const float* ta_bo1 = (const float*)d_in[20];
    const float* ta_Wo2 = (const float*)d_in[21]; const float* ta_bo2 = (const float*)d_in[22];
    const float* g_Wxs = (const float*)d_in[23];
    const float* g_Wxt = (const float*)d_in[24]; const float* g_bxt = (const float*)d_in[25];
    const float* g_Wh1 = (const float*)d_in[26]; const float* g_bh1 = (const float*)d_in[27];
    const float* g_Wh2 = (const float*)d_in[28]; const float* g_bh2 = (const float*)d_in[29];

    unsigned short* wsp = (unsigned short*)d_ws;
    unsigned short* qt  = wsp + 0L * P64;
    unsigned short* kt  = wsp + 1L * P64;
    unsigned short* vt  = wsp + 2L * P64;
    unsigned short* HSb = wsp + 3L * P64;
    unsigned short* HTb = wsp + 4L * P64;
    unsigned short* Wt  = wsp + 5L * P64;            // 6*64*192 bf16
    unsigned short* Wt8 = Wt + 6 * 12288;            // 8*64*64 bf16

    float* out = (float*)d_out;

    hipLaunchKernelGGL(wprep_all, dim3(416), dim3(256), 0, stream,
                       sa_Wq, sa_Wk, sa_Wv, ta_Wq, ta_Wk, ta_Wv,
                       sa_Wo1, sa_Wo2, ta_Wo1, ta_Wo2, g_Wxs, g_Wxt, g_Wh1, g_Wh2,
                       Wt, Wt8);

    hipLaunchKernelGGL(fused_sattn, dim3(BB * TT), dim3(512), 0, stream,
                       X, TLE, Wt,
                       sa_bq, sa_bk, sa_bv, ta_bq, ta_bk, ta_bv,
                       qt, kt, vt, HSb);

    hipLaunchKernelGGL(tattn_kernel, dim3(BB * NN), dim3(192), 0, stream,
                       qt, kt, vt, kpm, HTb);

    hipLaunchKernelGGL(epi_kernel, dim3(PTOT / 64), dim3(256), 0, stream,
                       X, HSb, HTb, Wt8,
                       sa_bo1, sa_bo2, ta_bo1, ta_bo2, g_bxt, g_bh1, g_bh2,
                       out);
}